// Round 10
// baseline (223.403 us; speedup 1.0000x reference)
//
#include <hip/hip_runtime.h>

typedef _Float16 f16x4 __attribute__((ext_vector_type(4)));
typedef _Float16 f16x8 __attribute__((ext_vector_type(8)));
typedef float    f32x4 __attribute__((ext_vector_type(4)));
typedef unsigned int u32x2 __attribute__((ext_vector_type(2)));

#if __has_builtin(__builtin_amdgcn_exp2f)
#define EXP2F __builtin_amdgcn_exp2f
#else
#define EXP2F exp2f
#endif
#if __has_builtin(__builtin_amdgcn_rcpf)
#define RCPF __builtin_amdgcn_rcpf
#else
#define RCPF(x) (1.0f/(x))
#endif

#define K2 2.8853900817779268f   // 2*log2(e)

// tanh folded: tanh(y) = 1 - 2*r, r = 1/(exp2(K2*y)+1).  We propagate r and
// fold the affine (1-2r) into the next layer's weights/biases.  Inputs arrive
// pre-scaled by K2 (folded into W/b), so per activation: exp2 + add + rcp.
static __device__ __forceinline__ float sigr(float d) {
    return RCPF(EXP2F(d) + 1.0f);
}

static __device__ __forceinline__ unsigned pkrtz(float a, float b) {
    auto t = __builtin_amdgcn_cvt_pkrtz(a, b);
    return __builtin_bit_cast(unsigned, t);
}

static __device__ __forceinline__ f32x4 mfma16(f16x4 a, f16x4 b, f32x4 c) {
#if __has_builtin(__builtin_amdgcn_mfma_f32_16x16x16f16)
    return __builtin_amdgcn_mfma_f32_16x16x16f16(a, b, c, 0, 0, 0);
#else
    f16x8 a8 = {a[0], a[1], a[2], a[3], 0, 0, 0, 0};
    f16x8 b8 = {b[0], b[1], b[2], b[3], 0, 0, 0, 0};
    return __builtin_amdgcn_mfma_f32_16x16x32_f16(a8, b8, c, 0, 0, 0);
#endif
}

// Barrier WITHOUT vmcnt drain (validated R8/R9): cross-wave communication is
// exclusively LDS; gout stores / u loads are wave-private.
static __device__ __forceinline__ void barrier_lds() {
    asm volatile("s_waitcnt lgkmcnt(0)\n\ts_barrier" ::: "memory");
}

// R9 structure + SEEDED ANTI-PHASE.
// Diagnosis: the 2 independent blocks/CU launch in-phase and, having
// identical deterministic instruction streams, STAY in-phase -> both stall
// at every barrier together (VALUBusy 46% ~= exactly half of the 2-wave
// issue capacity).  Fix: skew one block of each co-resident pair by ~half a
// feval period (s_sleep(8) ~= 512 cyc) once, after setup.  With identical
// cadences the offset self-preserves, so each SIMD's two waves alternate
// compute/stall -> barrier latency hidden by construction.
// Pairing under undefined dispatch is hedged: (bid ^ bid>>8)&1 desyncs both
// (2i,2i+1) and (b,b+256) pairings; worst case half the CUs benefit.
extern "C" __global__ __launch_bounds__(256, 2)
void rk4_kernel(const float* __restrict__ gu,  const float* __restrict__ gx0,
                const float* __restrict__ gW1, const float* __restrict__ gb1,
                const float* __restrict__ gW2, const float* __restrict__ gb2,
                const float* __restrict__ gW3, const float* __restrict__ gb3,
                const float* __restrict__ gxm, const float* __restrict__ gxs,
                const float* __restrict__ gum, const float* __restrict__ gus,
                float* __restrict__ gout)
{
    constexpr int T = 128;
    const int tid  = threadIdx.x;
    const int lane = tid & 63;
    const int w    = tid >> 6;
    const int c    = lane & 15;
    const int g    = lane >> 4;
    const int batch = blockIdx.x * 16 + c;

    // rows 72 halves = 144B stride -> conflict-free b128 reads.
    __shared__ __align__(16) _Float16 hb[2][16][72];

    // ---- fragments (one-time; weights L2-resident) ----
    // L1 A (16x16x16): K2*W1, real k=0..3 on g==0.
    f16x4 aW1;
#pragma unroll
    for (int j = 0; j < 4; ++j)
        aW1[j] = (_Float16)((g == 0) ? K2 * gW1[j * 64 + w * 16 + c] : 0.0f);

    // L2 A (16x16x32 x2): -2*K2*W2  (r-feed fold + exp2 pre-scale)
    f16x8 aW2[2];
#pragma unroll
    for (int kt = 0; kt < 2; ++kt)
#pragma unroll
        for (int j = 0; j < 8; ++j) {
            int k = kt * 32 + g * 8 + j;
            aW2[kt][j] = (_Float16)(-2.0f * K2 * gW2[k * 64 + w * 16 + c]);
        }

    // L3 A (16x16x32 x2): -2*W3, rows m=c (real c<3)
    f16x8 aW3[2];
#pragma unroll
    for (int kt = 0; kt < 2; ++kt)
#pragma unroll
        for (int j = 0; j < 8; ++j) {
            int k = kt * 32 + g * 8 + j;
            aW3[kt][j] = (_Float16)((c < 3) ? -2.0f * gW3[k * 3 + c] : 0.0f);
        }

    // C-frags (rows w*16+g*4+r): cb1 = K2*b1; cb2 = K2*(b2 + rowsum W2)
    f32x4 cb1, cb2;
#pragma unroll
    for (int r = 0; r < 4; ++r) {
        int row = w * 16 + g * 4 + r;
        cb1[r] = K2 * gb1[row];
        float rs = gb2[row];
        for (int k = 0; k < 64; ++k) rs += gW2[k * 64 + row];
        cb2[r] = K2 * rs;
    }

    // L3 consts: b3 + rowsum(W3) + greybox consts (+ per-step u term).
    const float xs0 = gxs[0], xs1 = gxs[1], xs2 = gxs[2];
    const float ig0 = 1.0f / (5.0f * xs0);
    const float ig1 = 1.0f / (5.0f * xs1);
    const float ig2 = 1.0f / (5.0f * xs2);
    const float ku  = gus[0] * ig0;
    float rs3[3];
#pragma unroll
    for (int m = 0; m < 3; ++m) {
        float s = gb3[m];
        for (int k = 0; k < 64; ++k) s += gW3[k * 3 + m];
        rs3[m] = s;
    }
    f32x4 cgb;
    cgb[0] = rs3[0] + (gum[0] - gxm[0]) * ig0;   // + u-term per step
    cgb[1] = rs3[1] - gxm[1] * ig1;
    cgb[2] = rs3[2] - gxm[2] * ig2;
    cgb[3] = 0.0f;
    const float cgb0_base = cgb[0];

    float x0v = gx0[batch * 3 + 0];
    float x1v = gx0[batch * 3 + 1];
    float x2v = gx0[batch * 3 + 2];

    // ---- seed anti-phase between the two co-resident blocks (see header) ----
    if (((blockIdx.x >> 8) ^ blockIdx.x) & 1)
        __builtin_amdgcn_s_sleep(8);     // ~512 cyc ~= half a feval period

    auto feval = [&](float e0, float e1, float e2, float ue,
                     float& o0, float& o1, float& o2) {
        // Z B-frag (16x16x16): k=0..3 -> (x0,x1,x2,u) on g==0 lanes.
        unsigned z01 = 0u, z23 = 0u;
        if (g == 0) { z01 = pkrtz(e0, e1); z23 = pkrtz(e2, ue); }
        u32x2 zi = {z01, z23};
        f16x4 zb = __builtin_bit_cast(f16x4, zi);

        // L1: d1 = K2*(W1 z + b1); r1 = sigr(d1)
        f32x4 d1 = mfma16(aW1, zb, cb1);
        u32x2 hw = {pkrtz(sigr(d1[0]), sigr(d1[1])),
                    pkrtz(sigr(d1[2]), sigr(d1[3]))};
        *(u32x2*)&hb[0][c][w * 16 + g * 4] = hw;
        barrier_lds();
        f16x8 hA0 = *(const f16x8*)&hb[0][c][g * 8];
        f16x8 hA1 = *(const f16x8*)&hb[0][c][32 + g * 8];

        // L2: d2 = K2*(b2 + rowsumW2) + (-2*K2*W2) r1 ; r2 = sigr(d2)
        f32x4 d2 = __builtin_amdgcn_mfma_f32_16x16x32_f16(aW2[0], hA0, cb2, 0, 0, 0);
        d2 = __builtin_amdgcn_mfma_f32_16x16x32_f16(aW2[1], hA1, d2, 0, 0, 0);
        u32x2 qw = {pkrtz(sigr(d2[0]), sigr(d2[1])),
                    pkrtz(sigr(d2[2]), sigr(d2[3]))};
        *(u32x2*)&hb[1][c][w * 16 + g * 4] = qw;
        barrier_lds();
        f16x8 hB0 = *(const f16x8*)&hb[1][c][g * 8];
        f16x8 hB1 = *(const f16x8*)&hb[1][c][32 + g * 8];

        // L3: xdot rows (m = g*4+r, real m<3) = (-2*W3) r2 + consts
        f32x4 d3 = __builtin_amdgcn_mfma_f32_16x16x32_f16(aW3[0], hB0, cgb, 0, 0, 0);
        d3 = __builtin_amdgcn_mfma_f32_16x16x32_f16(aW3[1], hB1, d3, 0, 0, 0);

        // greybox residual: -e/TAU (xstd cancels exactly)
        o0 = __builtin_fmaf(-0.2f, e0, d3[0]);
        o1 = __builtin_fmaf(-0.2f, e1, d3[1]);
        o2 = __builtin_fmaf(-0.2f, e2, d3[2]);
    };

    float ucur = gu[batch * T];
    float* orow = gout + (size_t)batch * (3 * T);

    for (int t = 0; t < T; ++t) {
        if (w == 0 && g == 0) {          // ys[t] = pre-step state
            orow[t * 3 + 0] = x0v;
            orow[t * 3 + 1] = x1v;
            orow[t * 3 + 2] = x2v;
        }
        float unext = gu[batch * T + ((t + 1 < T) ? t + 1 : t)];

        cgb[0] = __builtin_fmaf(ucur, ku, cgb0_base);   // per-step u const

        float a0, a1, a2, b0, b1v, b2v, c0, c1, c2, d0, d1v, d2v;
        feval(x0v, x1v, x2v, ucur, a0, a1, a2);
        feval(x0v + 0.5f * a0, x1v + 0.5f * a1, x2v + 0.5f * a2, ucur, b0, b1v, b2v);
        feval(x0v + 0.5f * b0, x1v + 0.5f * b1v, x2v + 0.5f * b2v, ucur, c0, c1, c2);
        feval(x0v + c0, x1v + c1, x2v + c2, ucur, d0, d1v, d2v);

        x0v += (1.0f / 6.0f) * (a0 + 2.0f * b0 + 2.0f * c0 + d0);
        x1v += (1.0f / 6.0f) * (a1 + 2.0f * b1v + 2.0f * c1 + d1v);
        x2v += (1.0f / 6.0f) * (a2 + 2.0f * b2v + 2.0f * c2 + d2v);
        ucur = unext;
    }
}

extern "C" void kernel_launch(void* const* d_in, const int* in_sizes, int n_in,
                              void* d_out, int out_size, void* d_ws, size_t ws_size,
                              hipStream_t stream) {
    const float* u  = (const float*)d_in[0];
    const float* x0 = (const float*)d_in[1];
    const float* W1 = (const float*)d_in[2];
    const float* b1 = (const float*)d_in[3];
    const float* W2 = (const float*)d_in[4];
    const float* b2 = (const float*)d_in[5];
    const float* W3 = (const float*)d_in[6];
    const float* b3 = (const float*)d_in[7];
    const float* xm = (const float*)d_in[8];
    const float* xs = (const float*)d_in[9];
    const float* um = (const float*)d_in[10];
    const float* us = (const float*)d_in[11];
    // 8192 / 16 cols per block = 512 blocks x 256 threads (4 waves, H-split)
    rk4_kernel<<<512, 256, 0, stream>>>(u, x0, W1, b1, W2, b2, W3, b3,
                                        xm, xs, um, us, (float*)d_out);
}

// Round 11
// 222.026 us; speedup vs baseline: 1.0062x; 1.0062x over previous
//
#include <hip/hip_runtime.h>

typedef _Float16 f16x4 __attribute__((ext_vector_type(4)));
typedef _Float16 f16x8 __attribute__((ext_vector_type(8)));
typedef float    f32x4 __attribute__((ext_vector_type(4)));
typedef unsigned int u32x2 __attribute__((ext_vector_type(2)));

#if __has_builtin(__builtin_amdgcn_exp2f)
#define EXP2F __builtin_amdgcn_exp2f
#else
#define EXP2F exp2f
#endif
#if __has_builtin(__builtin_amdgcn_rcpf)
#define RCPF __builtin_amdgcn_rcpf
#else
#define RCPF(x) (1.0f/(x))
#endif

#define K2 2.8853900817779268f   // 2*log2(e)

// tanh folded: tanh(y) = 1 - 2*r, r = 1/(exp2(K2*y)+1).  We propagate r and
// fold the affine (1-2r) into the next layer's weights/biases.  Inputs arrive
// pre-scaled by K2 (folded into W/b), so per activation: exp2 + add + rcp.
static __device__ __forceinline__ float sigr(float d) {
    return RCPF(EXP2F(d) + 1.0f);
}

static __device__ __forceinline__ unsigned pkrtz(float a, float b) {
    auto t = __builtin_amdgcn_cvt_pkrtz(a, b);
    return __builtin_bit_cast(unsigned, t);
}

static __device__ __forceinline__ f32x4 mfma16(f16x4 a, f16x4 b, f32x4 c) {
#if __has_builtin(__builtin_amdgcn_mfma_f32_16x16x16f16)
    return __builtin_amdgcn_mfma_f32_16x16x16f16(a, b, c, 0, 0, 0);
#else
    f16x8 a8 = {a[0], a[1], a[2], a[3], 0, 0, 0, 0};
    f16x8 b8 = {b[0], b[1], b[2], b[3], 0, 0, 0, 0};
    return __builtin_amdgcn_mfma_f32_16x16x32_f16(a8, b8, c, 0, 0, 0);
#endif
}

// Barrier WITHOUT vmcnt drain (validated R8/R9): cross-wave communication is
// exclusively LDS; gout stores / u loads are wave-private.
static __device__ __forceinline__ void barrier_lds() {
    asm volatile("s_waitcnt lgkmcnt(0)\n\ts_barrier" ::: "memory");
}

static __device__ __forceinline__ void prio(int p) {
    if (p) __builtin_amdgcn_s_setprio(1);
    else   __builtin_amdgcn_s_setprio(0);
}

// R9 structure (best: 221 us) + s_setprio region bias (T5).
// The latency-critical regions (post-barrier ds_read -> MFMA chains) run at
// prio 1; the tails (trans/pack/bookkeeping) at prio 0.  With 2 independent
// blocks/CU, any jitter-induced offset makes one block's critical region
// coincide with the other's tail -- prio makes the critical region win issue
// arbitration, amplifying the offset (continuous de-phasing, vs the one-shot
// sleep of R10 which the in-phase attractor absorbed).
extern "C" __global__ __launch_bounds__(256, 2)
void rk4_kernel(const float* __restrict__ gu,  const float* __restrict__ gx0,
                const float* __restrict__ gW1, const float* __restrict__ gb1,
                const float* __restrict__ gW2, const float* __restrict__ gb2,
                const float* __restrict__ gW3, const float* __restrict__ gb3,
                const float* __restrict__ gxm, const float* __restrict__ gxs,
                const float* __restrict__ gum, const float* __restrict__ gus,
                float* __restrict__ gout)
{
    constexpr int T = 128;
    const int tid  = threadIdx.x;
    const int lane = tid & 63;
    const int w    = tid >> 6;
    const int c    = lane & 15;
    const int g    = lane >> 4;
    const int batch = blockIdx.x * 16 + c;

    // rows 72 halves = 144B stride -> conflict-free b128 reads.
    __shared__ __align__(16) _Float16 hb[2][16][72];

    // ---- fragments (one-time; weights L2-resident) ----
    // L1 A (16x16x16): K2*W1, real k=0..3 on g==0.
    f16x4 aW1;
#pragma unroll
    for (int j = 0; j < 4; ++j)
        aW1[j] = (_Float16)((g == 0) ? K2 * gW1[j * 64 + w * 16 + c] : 0.0f);

    // L2 A (16x16x32 x2): -2*K2*W2  (r-feed fold + exp2 pre-scale)
    f16x8 aW2[2];
#pragma unroll
    for (int kt = 0; kt < 2; ++kt)
#pragma unroll
        for (int j = 0; j < 8; ++j) {
            int k = kt * 32 + g * 8 + j;
            aW2[kt][j] = (_Float16)(-2.0f * K2 * gW2[k * 64 + w * 16 + c]);
        }

    // L3 A (16x16x32 x2): -2*W3, rows m=c (real c<3)
    f16x8 aW3[2];
#pragma unroll
    for (int kt = 0; kt < 2; ++kt)
#pragma unroll
        for (int j = 0; j < 8; ++j) {
            int k = kt * 32 + g * 8 + j;
            aW3[kt][j] = (_Float16)((c < 3) ? -2.0f * gW3[k * 3 + c] : 0.0f);
        }

    // C-frags (rows w*16+g*4+r): cb1 = K2*b1; cb2 = K2*(b2 + rowsum W2)
    f32x4 cb1, cb2;
#pragma unroll
    for (int r = 0; r < 4; ++r) {
        int row = w * 16 + g * 4 + r;
        cb1[r] = K2 * gb1[row];
        float rs = gb2[row];
        for (int k = 0; k < 64; ++k) rs += gW2[k * 64 + row];
        cb2[r] = K2 * rs;
    }

    // L3 consts: b3 + rowsum(W3) + greybox consts (+ per-step u term).
    const float xs0 = gxs[0], xs1 = gxs[1], xs2 = gxs[2];
    const float ig0 = 1.0f / (5.0f * xs0);
    const float ig1 = 1.0f / (5.0f * xs1);
    const float ig2 = 1.0f / (5.0f * xs2);
    const float ku  = gus[0] * ig0;
    float rs3[3];
#pragma unroll
    for (int m = 0; m < 3; ++m) {
        float s = gb3[m];
        for (int k = 0; k < 64; ++k) s += gW3[k * 3 + m];
        rs3[m] = s;
    }
    f32x4 cgb;
    cgb[0] = rs3[0] + (gum[0] - gxm[0]) * ig0;   // + u-term per step
    cgb[1] = rs3[1] - gxm[1] * ig1;
    cgb[2] = rs3[2] - gxm[2] * ig2;
    cgb[3] = 0.0f;
    const float cgb0_base = cgb[0];

    float x0v = gx0[batch * 3 + 0];
    float x1v = gx0[batch * 3 + 1];
    float x2v = gx0[batch * 3 + 2];

    auto feval = [&](float e0, float e1, float e2, float ue,
                     float& o0, float& o1, float& o2) {
        // Z B-frag (16x16x16): k=0..3 -> (x0,x1,x2,u) on g==0 lanes.
        unsigned z01 = 0u, z23 = 0u;
        if (g == 0) { z01 = pkrtz(e0, e1); z23 = pkrtz(e2, ue); }
        u32x2 zi = {z01, z23};
        f16x4 zb = __builtin_bit_cast(f16x4, zi);

        // L1: d1 = K2*(W1 z + b1); r1 = sigr(d1)
        prio(1);
        f32x4 d1 = mfma16(aW1, zb, cb1);
        prio(0);
        u32x2 hw = {pkrtz(sigr(d1[0]), sigr(d1[1])),
                    pkrtz(sigr(d1[2]), sigr(d1[3]))};
        *(u32x2*)&hb[0][c][w * 16 + g * 4] = hw;
        barrier_lds();
        prio(1);
        f16x8 hA0 = *(const f16x8*)&hb[0][c][g * 8];
        f16x8 hA1 = *(const f16x8*)&hb[0][c][32 + g * 8];

        // L2: d2 = K2*(b2 + rowsumW2) + (-2*K2*W2) r1 ; r2 = sigr(d2)
        f32x4 d2 = __builtin_amdgcn_mfma_f32_16x16x32_f16(aW2[0], hA0, cb2, 0, 0, 0);
        d2 = __builtin_amdgcn_mfma_f32_16x16x32_f16(aW2[1], hA1, d2, 0, 0, 0);
        prio(0);
        u32x2 qw = {pkrtz(sigr(d2[0]), sigr(d2[1])),
                    pkrtz(sigr(d2[2]), sigr(d2[3]))};
        *(u32x2*)&hb[1][c][w * 16 + g * 4] = qw;
        barrier_lds();
        prio(1);
        f16x8 hB0 = *(const f16x8*)&hb[1][c][g * 8];
        f16x8 hB1 = *(const f16x8*)&hb[1][c][32 + g * 8];

        // L3: xdot rows (m = g*4+r, real m<3) = (-2*W3) r2 + consts
        f32x4 d3 = __builtin_amdgcn_mfma_f32_16x16x32_f16(aW3[0], hB0, cgb, 0, 0, 0);
        d3 = __builtin_amdgcn_mfma_f32_16x16x32_f16(aW3[1], hB1, d3, 0, 0, 0);
        prio(0);

        // greybox residual: -e/TAU (xstd cancels exactly)
        o0 = __builtin_fmaf(-0.2f, e0, d3[0]);
        o1 = __builtin_fmaf(-0.2f, e1, d3[1]);
        o2 = __builtin_fmaf(-0.2f, e2, d3[2]);
    };

    float ucur = gu[batch * T];
    float* orow = gout + (size_t)batch * (3 * T);

    for (int t = 0; t < T; ++t) {
        if (w == 0 && g == 0) {          // ys[t] = pre-step state
            orow[t * 3 + 0] = x0v;
            orow[t * 3 + 1] = x1v;
            orow[t * 3 + 2] = x2v;
        }
        float unext = gu[batch * T + ((t + 1 < T) ? t + 1 : t)];

        cgb[0] = __builtin_fmaf(ucur, ku, cgb0_base);   // per-step u const

        float a0, a1, a2, b0, b1v, b2v, c0, c1, c2, d0, d1v, d2v;
        feval(x0v, x1v, x2v, ucur, a0, a1, a2);
        feval(x0v + 0.5f * a0, x1v + 0.5f * a1, x2v + 0.5f * a2, ucur, b0, b1v, b2v);
        feval(x0v + 0.5f * b0, x1v + 0.5f * b1v, x2v + 0.5f * b2v, ucur, c0, c1, c2);
        feval(x0v + c0, x1v + c1, x2v + c2, ucur, d0, d1v, d2v);

        x0v += (1.0f / 6.0f) * (a0 + 2.0f * b0 + 2.0f * c0 + d0);
        x1v += (1.0f / 6.0f) * (a1 + 2.0f * b1v + 2.0f * c1 + d1v);
        x2v += (1.0f / 6.0f) * (a2 + 2.0f * b2v + 2.0f * c2 + d2v);
        ucur = unext;
    }
}

extern "C" void kernel_launch(void* const* d_in, const int* in_sizes, int n_in,
                              void* d_out, int out_size, void* d_ws, size_t ws_size,
                              hipStream_t stream) {
    const float* u  = (const float*)d_in[0];
    const float* x0 = (const float*)d_in[1];
    const float* W1 = (const float*)d_in[2];
    const float* b1 = (const float*)d_in[3];
    const float* W2 = (const float*)d_in[4];
    const float* b2 = (const float*)d_in[5];
    const float* W3 = (const float*)d_in[6];
    const float* b3 = (const float*)d_in[7];
    const float* xm = (const float*)d_in[8];
    const float* xs = (const float*)d_in[9];
    const float* um = (const float*)d_in[10];
    const float* us = (const float*)d_in[11];
    // 8192 / 16 cols per block = 512 blocks x 256 threads (4 waves, H-split)
    rk4_kernel<<<512, 256, 0, stream>>>(u, x0, W1, b1, W2, b2, W3, b3,
                                        xm, xs, um, us, (float*)d_out);
}